// Round 36
// baseline (1099.091 us; speedup 1.0000x reference)
//
#include <hip/hip_runtime.h>
#include <hip/hip_fp16.h>

// GaussianKernelLayer — round 36: MFMA with C/D row-interleave FIX + verify
// that samples ALL intra-tile offsets.
// out[n] = norm * sum_m (w[m]-mean(w)) * exp(-|x_n - c_m|^2 / 32), sigma=4, D=32
//
// r35 FAIL (6.2e-32, repair silent) => gmain error is a within-tile row
// permutation with fixed point 0, invisible to a verify that sampled only
// intra-tile offset 0 (rows b*1024). Hypothesis: true C/D row = (lane>>4) +
// 4*reg (interleave swap; fixed points g==q: rows 0,5,10,15). Fix: write row
// g+4q. Verify now samples rows b*1024+(b&15) (all 16 offsets) with tol 3e-33
// -> ANY remaining permutation triggers the r34-proven repair (still PASS).
// dur_us: ~100us = maps right; ~950us = repair active.
// ws ints: [0..63] flags, [64]=cen mode, [65]=wts mode, [66]=x mode.

#define QN 65536
#define QM 4096
#define QD 32
#define LOG2E 1.4426950408889634074

typedef __bf16 bf16x8 __attribute__((ext_vector_type(8)));
typedef float  f32x4  __attribute__((ext_vector_type(4)));

#if __has_builtin(__builtin_amdgcn_exp2f)
#define EXP2F(v) __builtin_amdgcn_exp2f(v)
#else
#define EXP2F(v) __builtin_exp2f(v)
#endif

// modes: 0=f32, 1=f64, 2=bf16, 3=fp16
__device__ __forceinline__ float ldf(const void* p, size_t i, int m) {
    if (m == 0) return ((const float*)p)[i];
    if (m == 1) return (float)((const double*)p)[i];
    if (m == 2) {
        union { unsigned u; float f; } c;
        c.u = ((unsigned)((const unsigned short*)p)[i]) << 16;
        return c.f;
    }
    return __half2float(((const __half*)p)[i]);
}
__device__ __forceinline__ double lddd(const void* p, size_t i, int m) {
    if (m == 1) return ((const double*)p)[i];
    return (double)ldf(p, i, m);
}
__device__ __forceinline__ int pat16(unsigned short w) {
    const unsigned e = (w >> 7) & 0xFF;
    return (e >= 100 && e <= 135) ? 1 : 0;
}

// ---------------------------------------------------------------------------
// 0) Sniffer (r33/r34-proven): per-buffer {f32,f64,bf16,fp16}.
// ---------------------------------------------------------------------------
__global__ void ksniff(const void* cen, const void* wts, const void* x,
                       int* mode)
{
    __shared__ int cnt[6];
    const int tid = threadIdx.x;
    if (tid < 6) cnt[tid] = 0;
    __syncthreads();
    const void* bufs[3] = {cen, wts, x};
    const int np[3] = {4096, 2048, 4096};
    for (int b = 0; b < 3; ++b) {
        const unsigned short* u = (const unsigned short*)bufs[b];
        int pe = 0, po = 0;
        for (int i = tid; i < np[b]; i += 256) {
            pe += pat16(u[2 * i]);
            po += pat16(u[2 * i + 1]);
        }
        if (pe) atomicAdd(&cnt[b * 2 + 0], pe);
        if (po) atomicAdd(&cnt[b * 2 + 1], po);
    }
    __syncthreads();
    if (tid < 3) {
        const int n = np[tid];
        const int A = cnt[tid * 2 + 0], B = cnt[tid * 2 + 1];
        int m;
        if      (A * 100 >= n * 93) m = 2;   // bf16
        else if (A * 100 >= n * 45) m = 3;   // fp16
        else if (B * 100 >= n * 85) m = 0;   // f32
        else                        m = 1;   // f64
        mode[64 + tid] = m;
    }
}

// ---------------------------------------------------------------------------
// 1) MFMA main: per wave one 16-row x-tile vs all M.
//    A/B: idx = lane&15, k = (lane>>4)*8+j (shared k-perm, dot-safe).
//    C/D (r36 hypothesis): col = lane&15, row = (lane>>4) + 4*reg.
// ---------------------------------------------------------------------------
__global__ __launch_bounds__(256)
void gmain(const void* __restrict__ x, const void* __restrict__ cen,
           const void* __restrict__ wts, float* __restrict__ out,
           const int* __restrict__ mode, float normf)
{
    __shared__ __attribute__((aligned(16))) __bf16 s_c[8192]; // 16 KB frags
    __shared__ float2 s_p[256];
    __shared__ double s_red[256];

    const int mc = mode[64], mw = mode[65], mx = mode[66];
    const int tid  = threadIdx.x;
    const int wave = tid >> 6, lane = tid & 63;
    const int c16  = lane & 15, g = lane >> 4;
    const int n0   = (blockIdx.x * 4 + wave) * 16;

    const float C1f = (float)(-LOG2E / 32.0);
    const float C2f = (float)( LOG2E / 16.0);

    double s = 0.0;
    #pragma unroll
    for (int i = 0; i < QM / 256; ++i) s += lddd(wts, tid + i * 256, mw);
    s_red[tid] = s;
    __syncthreads();
    for (int off = 128; off > 0; off >>= 1) {
        if (tid < off) s_red[tid] += s_red[tid + off];
        __syncthreads();
    }
    const double mean = s_red[0] * (1.0 / QM);

    bf16x8 a;
    float xsq;
    {
        const size_t xb = (size_t)(n0 + c16) * QD + g * 8;
        float p = 0.f;
        #pragma unroll
        for (int j = 0; j < 8; ++j) {
            const float v = ldf(x, xb + j, mx);
            p = fmaf(v, v, p);
            a[j] = (__bf16)v;
        }
        p += __shfl_xor(p, 16, 64);
        p += __shfl_xor(p, 32, 64);
        xsq = p;                       // lane l holds xsq of row (l&15)
    }

    f32x4 part = {0.f, 0.f, 0.f, 0.f};

    for (int pass = 0; pass < 16; ++pass) {
        const int base = pass * 256;
        __syncthreads();
        {
            #pragma unroll 8
            for (int i = 0; i < 32; ++i) {
                const int e = tid + i * 256;
                const int mloc = e >> 5, d = e & 31;
                const int ct = mloc >> 4, r = mloc & 15, kg = d >> 3, j = d & 7;
                s_c[((ct * 64) + kg * 16 + r) * 8 + j] =
                    (__bf16)ldf(cen, (size_t)base * QD + e, mc);
            }
            double csq = 0.0;
            #pragma unroll
            for (int d = 0; d < QD; ++d) {
                const double c = lddd(cen, (size_t)(base + tid) * QD + d, mc);
                csq += c * c;
            }
            s_p[tid] = make_float2((float)((-LOG2E / 32.0) * csq),
                                   (float)(lddd(wts, base + tid, mw) - mean));
        }
        __syncthreads();

        #pragma unroll
        for (int ct = 0; ct < 16; ++ct) {
            bf16x8 b = *(const bf16x8*)&s_c[(ct * 64 + lane) * 8];
            f32x4 acc = {0.f, 0.f, 0.f, 0.f};
            acc = __builtin_amdgcn_mfma_f32_16x16x32_bf16(a, b, acc, 0, 0, 0);
            const float2 pr = s_p[ct * 16 + c16];   // col = lane&15
            #pragma unroll
            for (int q = 0; q < 4; ++q)
                part[q] = fmaf(EXP2F(fmaf(C2f, acc[q], pr.x)), pr.y, part[q]);
        }
    }

    // reduce over the 16 columns (butterfly on c16 bits)
    #pragma unroll
    for (int mask = 1; mask <= 8; mask <<= 1) {
        #pragma unroll
        for (int q = 0; q < 4; ++q)
            part[q] += __shfl_xor(part[q], mask, 64);
    }

    // r36 FIX: output row for reg q is g + 4*q (interleaved), not g*4+q.
    float xsq_out[4];
    #pragma unroll
    for (int q = 0; q < 4; ++q)
        xsq_out[q] = __shfl(xsq, g + 4 * q, 64);   // lane r holds xsq of row r

    if (c16 == 0) {   // lanes 0,16,32,48 write rows g + 4q
        #pragma unroll
        for (int q = 0; q < 4; ++q)
            out[n0 + g + 4 * q] =
                normf * EXP2F(C1f * xsq_out[q]) * part[q];
    }
}

// ---------------------------------------------------------------------------
// 2) Verify: 64 rows covering ALL 16 intra-tile offsets (row = b*1024+(b&15)),
//    literal formula, proven decode; tol 3e-33 (noise ~5e-34, perm ~3e-32).
// ---------------------------------------------------------------------------
__global__ __launch_bounds__(256)
void gverify(const void* __restrict__ x, const void* __restrict__ cen,
             const void* __restrict__ wts, const float* __restrict__ out,
             int* __restrict__ flags, float normf)
{
    __shared__ double sred[256];
    __shared__ float  sf[256];

    const int mc = flags[64], mw = flags[65], mx = flags[66];
    const int tid = threadIdx.x;
    const int row = blockIdx.x * 1024 + (blockIdx.x & 15);

    double s = 0.0;
    for (int i = tid; i < QM; i += 256) s += lddd(wts, i, mw);
    sred[tid] = s;
    __syncthreads();
    for (int off = 128; off > 0; off >>= 1) {
        if (tid < off) sred[tid] += sred[tid + off];
        __syncthreads();
    }
    const double mean = sred[0] * (1.0 / QM);

    float xv[QD];
    #pragma unroll
    for (int d = 0; d < QD; ++d)
        xv[d] = ldf(x, (size_t)row * QD + d, mx);

    const float kf = (float)(-LOG2E / 32.0);

    float part = 0.f;
    for (int m = tid; m < QM; m += 256) {
        const size_t cb = (size_t)m * QD;
        float p0 = 0.f, p1 = 0.f, p2 = 0.f, p3 = 0.f;
        #pragma unroll
        for (int d = 0; d < 8; ++d) {
            const float t0 = xv[d]      - ldf(cen, cb + d,      mc);
            const float t1 = xv[d + 8]  - ldf(cen, cb + d + 8,  mc);
            const float t2 = xv[d + 16] - ldf(cen, cb + d + 16, mc);
            const float t3 = xv[d + 24] - ldf(cen, cb + d + 24, mc);
            p0 = fmaf(t0, t0, p0);
            p1 = fmaf(t1, t1, p1);
            p2 = fmaf(t2, t2, p2);
            p3 = fmaf(t3, t3, p3);
        }
        const float d2 = (p0 + p1) + (p2 + p3);
        part = fmaf(EXP2F(kf * d2), (float)(lddd(wts, m, mw) - mean), part);
    }
    sf[tid] = part;
    __syncthreads();
    for (int off = 128; off > 0; off >>= 1) {
        if (tid < off) sf[tid] += sf[tid + off];
        __syncthreads();
    }

    if (tid == 0) {
        const float val  = normf * sf[0];
        const float diff = __builtin_fabsf(out[row] - val);
        flags[blockIdx.x] = (diff > 3.0e-33f) ? 1 : 0;
    }
}

// ---------------------------------------------------------------------------
// 3) Fix: early-exit if clean; else r34's PASSING 760us gfast body.
// ---------------------------------------------------------------------------
__global__ __launch_bounds__(256)
void gfix(const void* __restrict__ x, const void* __restrict__ cen,
          const void* __restrict__ wts, float* __restrict__ out,
          const int* __restrict__ flags, float normf)
{
    __shared__ int sbad;
    __shared__ double sred[256];
    __shared__ float  swb[QM];
    __shared__ __attribute__((aligned(16))) float scen[256 * QD];

    const int tid = threadIdx.x;
    if (tid == 0) {
        int b = 0;
        for (int i = 0; i < 64; ++i) b |= flags[i];
        sbad = b;
    }
    __syncthreads();
    if (!sbad) return;

    const int mc = flags[64], mw = flags[65], mx = flags[66];

    double s = 0.0;
    for (int i = tid; i < QM; i += 256) s += lddd(wts, i, mw);
    sred[tid] = s;
    __syncthreads();
    for (int off = 128; off > 0; off >>= 1) {
        if (tid < off) sred[tid] += sred[tid + off];
        __syncthreads();
    }
    const double mean = sred[0] * (1.0 / QM);

    for (int i = tid; i < QM; i += 256)
        swb[i] = (float)(lddd(wts, i, mw) - mean);

    const int n = blockIdx.x * 256 + tid;
    float xv[QD];
    #pragma unroll
    for (int d = 0; d < QD; ++d)
        xv[d] = (n < QN) ? ldf(x, (size_t)n * QD + d, mx) : 0.0f;

    const float kf = (float)(-LOG2E / 32.0);
    float acc = 0.0f;

    for (int pass = 0; pass < 16; ++pass) {
        __syncthreads();
        #pragma unroll 8
        for (int k = 0; k < 32; ++k) {
            const int idx = tid + k * 256;
            scen[idx] = ldf(cen, (size_t)pass * 8192 + idx, mc);
        }
        __syncthreads();

        #pragma unroll 2
        for (int j = 0; j < 256; ++j) {
            const f32x4* cp = (const f32x4*)&scen[j * QD];
            float p0 = 0.f, p1 = 0.f, p2 = 0.f, p3 = 0.f;
            #pragma unroll
            for (int q = 0; q < 2; ++q) {
                const f32x4 c0 = cp[q];
                const f32x4 c1 = cp[q + 2];
                const f32x4 c2 = cp[q + 4];
                const f32x4 c3 = cp[q + 6];
                #pragma unroll
                for (int r = 0; r < 4; ++r) {
                    const float t0 = xv[q * 4 + r]      - c0[r];
                    const float t1 = xv[8 + q * 4 + r]  - c1[r];
                    const float t2 = xv[16 + q * 4 + r] - c2[r];
                    const float t3 = xv[24 + q * 4 + r] - c3[r];
                    p0 = fmaf(t0, t0, p0);
                    p1 = fmaf(t1, t1, p1);
                    p2 = fmaf(t2, t2, p2);
                    p3 = fmaf(t3, t3, p3);
                }
            }
            const float d2 = (p0 + p1) + (p2 + p3);
            acc = fmaf(EXP2F(kf * d2), swb[pass * 256 + j], acc);
        }
    }

    if (n < QN) out[n] = normf * acc;
}

// ---------------------------------------------------------------------------
extern "C" void kernel_launch(void* const* d_in, const int* in_sizes, int n_in,
                              void* d_out, int out_size, void* d_ws, size_t ws_size,
                              hipStream_t stream)
{
    const void* xp = nullptr; const void* cp = nullptr; const void* wp = nullptr;
    for (int i = 0; i < n_in; ++i) {
        if      (in_sizes[i] == QN * QD) xp = d_in[i];
        else if (in_sizes[i] == QM * QD) cp = d_in[i];
        else if (in_sizes[i] == QM)      wp = d_in[i];
    }
    if (!xp) xp = d_in[0];
    if (!cp) cp = d_in[1];
    if (!wp) wp = d_in[2];

    float* out = (float*)d_out;

    const double tp  = 6.283185307179586476925287;
    const double tp2 = tp * tp, tp4 = tp2 * tp2, tp8 = tp4 * tp4;
    const double nrm = 1.0 / ((tp8 * tp8) * 18446744073709551616.0);
    const float normf = (float)nrm;

    int* wsi = (int*)d_ws;

    hipLaunchKernelGGL(ksniff, dim3(1), dim3(256), 0, stream,
                       cp, wp, xp, wsi);
    hipLaunchKernelGGL(gmain, dim3(QN / 64), dim3(256), 0, stream,
                       xp, cp, wp, out, wsi, normf);
    hipLaunchKernelGGL(gverify, dim3(64), dim3(256), 0, stream,
                       xp, cp, wp, out, wsi, normf);
    hipLaunchKernelGGL(gfix, dim3(QN / 256), dim3(256), 0, stream,
                       xp, cp, wp, out, wsi, normf);
}